// Round 4
// baseline (380.581 us; speedup 1.0000x reference)
//
#include <hip/hip_runtime.h>
#include <hip/hip_bf16.h>

#define NQ   14
#define DIM  16384      // 2^14
#define BLK  1024
#define WMUL 0.6324555320336759f  // sqrt(2/5)

struct alignas(8) C2 { float x, y; };
__device__ inline C2 cmul(C2 a, C2 b){ return C2{a.x*b.x - a.y*b.y, a.x*b.y + a.y*b.x}; }
__device__ inline C2 cadd(C2 a, C2 b){ return C2{a.x+b.x, a.y+b.y}; }

// o = a*b (2x2 complex, row-major)
__device__ inline void mm2(const C2* a, const C2* b, C2* o) {
    o[0] = cadd(cmul(a[0],b[0]), cmul(a[1],b[2]));
    o[1] = cadd(cmul(a[0],b[1]), cmul(a[1],b[3]));
    o[2] = cadd(cmul(a[2],b[0]), cmul(a[3],b[2]));
    o[3] = cadd(cmul(a[2],b[1]), cmul(a[3],b[3]));
}

__device__ inline void build_gate(int ty, float t, C2* g) {
    float sn, cs;
    __sincosf(0.5f * t, &sn, &cs);
    if (ty == 0) {        // rx
        g[0] = C2{cs, 0.f}; g[1] = C2{0.f, -sn};
        g[2] = C2{0.f, -sn}; g[3] = C2{cs, 0.f};
    } else if (ty == 1) { // ry
        g[0] = C2{cs, 0.f}; g[1] = C2{-sn, 0.f};
        g[2] = C2{sn, 0.f}; g[3] = C2{cs, 0.f};
    } else {              // rz
        g[0] = C2{cs, -sn}; g[1] = C2{0.f, 0.f};
        g[2] = C2{0.f, 0.f}; g[3] = C2{cs, sn};
    }
}

__device__ const int TYPES[5][3] = {
    {0,1,2},  // XYZ
    {1,2,1},  // YZY
    {2,1,0},  // ZYX
    {0,2,0},  // XZX
    {1,2,1},  // YZY
};

// bank-conflict swizzle: fold upper nibbles into low nibble (pure fn of high bits)
__device__ inline uint32_t slotf(uint32_t i){ return i ^ (((i>>4) ^ (i>>8) ^ (i>>12)) & 15u); }

template<int B> __device__ inline uint32_t ins0(uint32_t t){
    return ((t & ~((1u<<B)-1u)) << 1) | (t & ((1u<<B)-1u));
}
// deposit tid's 10 bits into the complement of group bits B0<B1<B2<B3 (final positions)
template<int B0,int B1,int B2,int B3> __device__ inline uint32_t expand4(uint32_t t){
    return ins0<B3>(ins0<B2>(ins0<B1>(ins0<B0>(t))));
}
template<int B0,int B1,int B2,int B3> __device__ inline uint32_t idx16(uint32_t base, int r){
    return base | ((r&1)?(1u<<B0):0u) | ((r&2)?(1u<<B1):0u)
                | ((r&4)?(1u<<B2):0u) | ((r&8)?(1u<<B3):0u);
}

template<int B0,int B1,int B2,int B3>
__device__ inline void gatherLDS(C2* __restrict__ v, const C2* __restrict__ s, uint32_t tid){
    uint32_t base = expand4<B0,B1,B2,B3>(tid);
    #pragma unroll
    for (int r = 0; r < 16; ++r) v[r] = s[slotf(idx16<B0,B1,B2,B3>(base, r))];
}
template<int B0,int B1,int B2,int B3>
__device__ inline void scatterLDS(const C2* __restrict__ v, C2* __restrict__ s, uint32_t tid){
    uint32_t base = expand4<B0,B1,B2,B3>(tid);
    #pragma unroll
    for (int r = 0; r < 16; ++r) s[slotf(idx16<B0,B1,B2,B3>(base, r))] = v[r];
}

// rotation on local bit J with fused 2x2 matrix g[0..3] (LDS broadcast reads)
template<int J>
__device__ inline void rotg(C2* v, const C2* g){
    const C2 m00 = g[0], m01 = g[1], m10 = g[2], m11 = g[3];
    #pragma unroll
    for (int r = 0; r < 16; ++r){
        if (!(r & (1 << J))) {
            C2 a0 = v[r], a1 = v[r | (1 << J)];
            v[r]          = cadd(cmul(m00, a0), cmul(m01, a1));
            v[r | (1<<J)] = cadd(cmul(m10, a0), cmul(m11, a1));
        }
    }
}
// CNOT: control local bit C, target local bit T
template<int C, int T>
__device__ inline void cnotg(C2* v){
    #pragma unroll
    for (int r = 0; r < 16; ++r){
        if ((r & (1 << C)) && !(r & (1 << T))) {
            C2 t = v[r]; v[r] = v[r | (1 << T)]; v[r | (1 << T)] = t;
        }
    }
}

// LDS 130 KiB/WG -> 1 WG/CU -> 16 waves/CU = 4 waves/EU is the occupancy
// ceiling. Pin it with backend attributes so the allocator gets 512/4 = 128
// VGPRs (__launch_bounds__(1024,4) was ignored: VGPR stayed 64 and v[16]
// spilled ~790 MB/dispatch to scratch).
__global__
__attribute__((amdgpu_flat_work_group_size(BLK, BLK), amdgpu_waves_per_eu(4, 4)))
void qsim_kernel(
        const float* __restrict__ xr, const float* __restrict__ xi,
        const float* __restrict__ w, float* __restrict__ out) {
    __shared__ C2 s[DIM];          // 128 KiB statevector (swizzled layout)
    __shared__ C2 gm[5 * NQ * 4];  // 70 fused 2x2 complex gates
    __shared__ float red[BLK / 64];

    const int b   = blockIdx.x;
    const uint32_t tid = threadIdx.x;

    // ---- build fused gate matrices (threads 0..69) ----
    if (tid < 5 * NQ) {
        const int li = tid / NQ, q = tid % NQ;
        C2 M[4], G[4], T[4];
        #pragma unroll
        for (int j = 0; j < 3; ++j) {
            float t = w[3 * NQ * li + 3 * q + j] * WMUL;
            build_gate(TYPES[li][j], t, G);
            if (j == 0) { M[0]=G[0]; M[1]=G[1]; M[2]=G[2]; M[3]=G[3]; }
            else { mm2(G, M, T); M[0]=T[0]; M[1]=T[1]; M[2]=T[2]; M[3]=T[3]; }
        }
        #pragma unroll
        for (int k = 0; k < 4; ++k) gm[tid * 4 + k] = M[k];
    }
    __syncthreads();

    const float* xrb = xr + (size_t)b * DIM;
    const float* xib = xi + (size_t)b * DIM;

    C2 v[16];

    // qubit q <-> bit (13-q).  gm index: (li*NQ + q)*4
    #define GM(li, q) (&gm[((li) * NQ + (q)) * 4])

    for (int li = 0; li < 4; ++li) {
        // P1: bits {10,11,12,13} = qubits 3,2,1,0
        if (li == 0) {
            // first pass straight from global (coalesced: lanes vary low bits)
            #pragma unroll
            for (int r = 0; r < 16; ++r) {
                uint32_t i = tid | ((uint32_t)r << 10);
                v[r] = C2{xrb[i], xib[i]};
            }
        } else {
            gatherLDS<10,11,12,13>(v, s, tid);
        }
        rotg<3>(v, GM(li,0)); rotg<2>(v, GM(li,1)); rotg<1>(v, GM(li,2)); rotg<0>(v, GM(li,3));
        cnotg<3,2>(v); cnotg<2,1>(v); cnotg<1,0>(v);   // CNOT(0,1),(1,2),(2,3)
        scatterLDS<10,11,12,13>(v, s, tid);
        __syncthreads();

        // P2: bits {7,8,9,10} = qubits 6,5,4,3
        gatherLDS<7,8,9,10>(v, s, tid);
        rotg<2>(v, GM(li,4)); rotg<1>(v, GM(li,5)); rotg<0>(v, GM(li,6));
        cnotg<3,2>(v); cnotg<2,1>(v); cnotg<1,0>(v);   // CNOT(3,4),(4,5),(5,6)
        scatterLDS<7,8,9,10>(v, s, tid);
        __syncthreads();

        // P3: bits {4,5,6,7} = qubits 9,8,7,6
        gatherLDS<4,5,6,7>(v, s, tid);
        rotg<2>(v, GM(li,7)); rotg<1>(v, GM(li,8)); rotg<0>(v, GM(li,9));
        cnotg<3,2>(v); cnotg<2,1>(v); cnotg<1,0>(v);   // CNOT(6,7),(7,8),(8,9)
        scatterLDS<4,5,6,7>(v, s, tid);
        __syncthreads();

        // P4: bits {1,2,3,4} = qubits 12,11,10,9
        gatherLDS<1,2,3,4>(v, s, tid);
        rotg<2>(v, GM(li,10)); rotg<1>(v, GM(li,11)); rotg<0>(v, GM(li,12));
        cnotg<3,2>(v); cnotg<2,1>(v); cnotg<1,0>(v);   // CNOT(9,10),(10,11),(11,12)
        scatterLDS<1,2,3,4>(v, s, tid);
        __syncthreads();

        // P5: bits {0,1,2,13}: local0=q13, local1=q12, local2=q11(idle), local3=q0
        gatherLDS<0,1,2,13>(v, s, tid);
        rotg<0>(v, GM(li,13));
        cnotg<1,0>(v);   // CNOT(12,13)
        cnotg<0,3>(v);   // CNOT(13,0)
        scatterLDS<0,1,2,13>(v, s, tid);
        __syncthreads();
    }

    // ---- last layer (li=4): rotations only, 4 passes ----
    gatherLDS<10,11,12,13>(v, s, tid);
    rotg<3>(v, GM(4,0)); rotg<2>(v, GM(4,1)); rotg<1>(v, GM(4,2)); rotg<0>(v, GM(4,3));
    scatterLDS<10,11,12,13>(v, s, tid);
    __syncthreads();

    gatherLDS<6,7,8,9>(v, s, tid);
    rotg<3>(v, GM(4,4)); rotg<2>(v, GM(4,5)); rotg<1>(v, GM(4,6)); rotg<0>(v, GM(4,7));
    scatterLDS<6,7,8,9>(v, s, tid);
    __syncthreads();

    gatherLDS<2,3,4,5>(v, s, tid);
    rotg<3>(v, GM(4,8)); rotg<2>(v, GM(4,9)); rotg<1>(v, GM(4,10)); rotg<0>(v, GM(4,11));
    scatterLDS<2,3,4,5>(v, s, tid);
    __syncthreads();

    // final pass: bits {0,1,2,3}: local1=q12, local0=q13; fuse <Z_0> reduction
    gatherLDS<0,1,2,3>(v, s, tid);
    rotg<1>(v, GM(4,12)); rotg<0>(v, GM(4,13));

    // bit13 of this thread's indices = tid bit 9 (uniform per thread)
    float local = 0.f;
    #pragma unroll
    for (int r = 0; r < 16; ++r) local += v[r].x * v[r].x + v[r].y * v[r].y;
    if (tid & 512u) local = -local;

    #pragma unroll
    for (int off = 32; off > 0; off >>= 1) local += __shfl_down(local, off);
    const int lane = tid & 63, wid = tid >> 6;
    if (lane == 0) red[wid] = local;
    __syncthreads();
    if (tid == 0) {
        float t = 0.f;
        #pragma unroll
        for (int k = 0; k < BLK / 64; ++k) t += red[k];
        out[b] = t;
    }
}

extern "C" void kernel_launch(void* const* d_in, const int* in_sizes, int n_in,
                              void* d_out, int out_size, void* d_ws, size_t ws_size,
                              hipStream_t stream) {
    const float* xr = (const float*)d_in[0];
    const float* xi = (const float*)d_in[1];
    const float* w  = (const float*)d_in[2];
    float* out = (float*)d_out;
    const int B = out_size;  // 512
    qsim_kernel<<<B, BLK, 0, stream>>>(xr, xi, w, out);
}

// Round 5
// 195.508 us; speedup vs baseline: 1.9466x; 1.9466x over previous
//
#include <hip/hip_runtime.h>
#include <hip/hip_bf16.h>

#define NQ   14
#define DIM  16384      // 2^14
#define BLK  1024
#define WMUL 0.6324555320336759f  // sqrt(2/5)

struct alignas(8) C2 { float x, y; };
__device__ inline C2 cmul(C2 a, C2 b){ return C2{a.x*b.x - a.y*b.y, a.x*b.y + a.y*b.x}; }
__device__ inline C2 cadd(C2 a, C2 b){ return C2{a.x+b.x, a.y+b.y}; }

// o = a*b (2x2 complex, row-major)
__device__ inline void mm2(const C2* a, const C2* b, C2* o) {
    o[0] = cadd(cmul(a[0],b[0]), cmul(a[1],b[2]));
    o[1] = cadd(cmul(a[0],b[1]), cmul(a[1],b[3]));
    o[2] = cadd(cmul(a[2],b[0]), cmul(a[3],b[2]));
    o[3] = cadd(cmul(a[2],b[1]), cmul(a[3],b[3]));
}

__device__ inline void build_gate(int ty, float t, C2* g) {
    float sn, cs;
    __sincosf(0.5f * t, &sn, &cs);
    if (ty == 0) {        // rx
        g[0] = C2{cs, 0.f}; g[1] = C2{0.f, -sn};
        g[2] = C2{0.f, -sn}; g[3] = C2{cs, 0.f};
    } else if (ty == 1) { // ry
        g[0] = C2{cs, 0.f}; g[1] = C2{-sn, 0.f};
        g[2] = C2{sn, 0.f}; g[3] = C2{cs, 0.f};
    } else {              // rz
        g[0] = C2{cs, -sn}; g[1] = C2{0.f, 0.f};
        g[2] = C2{0.f, 0.f}; g[3] = C2{cs, sn};
    }
}

__device__ const int TYPES[5][3] = {
    {0,1,2},  // XYZ
    {1,2,1},  // YZY
    {2,1,0},  // ZYX
    {0,2,0},  // XZX
    {1,2,1},  // YZY
};

// bank-conflict swizzle; GF(2)-LINEAR: slotf(a|b) = slotf(a)^slotf(b) for disjoint a,b
__device__ inline constexpr uint32_t slotf(uint32_t i){
    return i ^ (((i>>4) ^ (i>>8) ^ (i>>12)) & 15u);
}

template<int B> __device__ inline uint32_t ins0(uint32_t t){
    return ((t & ~((1u<<B)-1u)) << 1) | (t & ((1u<<B)-1u));
}
// deposit t's 11 bits into the complement of group bits B0<B1<B2 (final positions)
template<int B0,int B1,int B2> __device__ inline uint32_t expand3(uint32_t t){
    return ins0<B2>(ins0<B1>(ins0<B0>(t)));
}
template<int B0,int B1,int B2> __device__ inline constexpr uint32_t rmask3(int r){
    return ((r&1)?(1u<<B0):0u) | ((r&2)?(1u<<B1):0u) | ((r&4)?(1u<<B2):0u);
}

// rotation on local bit J (4 pairs within v[8])
template<int J>
__device__ inline void rot8(C2* v, const C2* g){
    const C2 m00 = g[0], m01 = g[1], m10 = g[2], m11 = g[3];
    #pragma unroll
    for (int r = 0; r < 8; ++r){
        if (!(r & (1 << J))) {
            C2 a0 = v[r], a1 = v[r | (1 << J)];
            v[r]          = cadd(cmul(m00, a0), cmul(m01, a1));
            v[r | (1<<J)] = cadd(cmul(m10, a0), cmul(m11, a1));
        }
    }
}
// CNOT: control local bit C, target local bit T (register renaming, ~free)
template<int C, int T>
__device__ inline void cnot8(C2* v){
    #pragma unroll
    for (int r = 0; r < 8; ++r){
        if ((r & (1 << C)) && !(r & (1 << T))) {
            C2 tt = v[r]; v[r] = v[r | (1 << T)]; v[r | (1 << T)] = tt;
        }
    }
}

__global__ __launch_bounds__(BLK) void qsim_kernel(
        const float* __restrict__ xr, const float* __restrict__ xi,
        const float* __restrict__ w, float* __restrict__ out) {
    __shared__ C2 s[DIM];          // 128 KiB statevector (swizzled layout)
    __shared__ C2 gm[5 * NQ * 4];  // 70 fused 2x2 complex gates
    __shared__ float red[BLK / 64];

    const int b   = blockIdx.x;
    const uint32_t tid = threadIdx.x;

    // ---- build fused gate matrices (threads 0..69) ----
    if (tid < 5 * NQ) {
        const int li = tid / NQ, q = tid % NQ;
        C2 M[4], G[4], T[4];
        #pragma unroll
        for (int j = 0; j < 3; ++j) {
            float t = w[3 * NQ * li + 3 * q + j] * WMUL;
            build_gate(TYPES[li][j], t, G);
            if (j == 0) { M[0]=G[0]; M[1]=G[1]; M[2]=G[2]; M[3]=G[3]; }
            else { mm2(G, M, T); M[0]=T[0]; M[1]=T[1]; M[2]=T[2]; M[3]=T[3]; }
        }
        #pragma unroll
        for (int k = 0; k < 4; ++k) gm[tid * 4 + k] = M[k];
    }
    __syncthreads();

    const float* xrb = xr + (size_t)b * DIM;
    const float* xib = xi + (size_t)b * DIM;

    // qubit q <-> bit (13-q).  gm index: (li*NQ + q)*4
    #define GM(li, q) (&gm[((li) * NQ + (q)) * 4])

    // One pass: 2 sequential slabs (keeps live state at v[8] = 16 VGPRs).
    // Addressing: slot = slotf(expand3(t)) ^ slotf(rmask3(r))  [2nd term = imm const]
    #define PASS(B0, B1, B2, ...)                                                  \
        _Pragma("unroll 1")                                                        \
        for (uint32_t sl = 0; sl < 2; ++sl) {                                      \
            const uint32_t t  = tid + sl * BLK;                                    \
            const uint32_t sb = slotf(expand3<B0,B1,B2>(t));                       \
            C2 v[8];                                                               \
            _Pragma("unroll")                                                      \
            for (int r = 0; r < 8; ++r)                                            \
                v[r] = s[sb ^ slotf(rmask3<B0,B1,B2>(r))];                         \
            __VA_ARGS__                                                            \
            _Pragma("unroll")                                                      \
            for (int r = 0; r < 8; ++r)                                            \
                s[sb ^ slotf(rmask3<B0,B1,B2>(r))] = v[r];                         \
        }                                                                          \
        __syncthreads();

    for (int li = 0; li < 4; ++li) {
        // W1 bits{11,12,13}=q2,q1,q0: rot q0,q1,q2 + CNOT(0,1),(1,2); li==0 reads global
        #pragma unroll 1
        for (uint32_t sl = 0; sl < 2; ++sl) {
            const uint32_t t = tid + sl * BLK;
            C2 v[8];
            if (li == 0) {
                #pragma unroll
                for (int r = 0; r < 8; ++r) {
                    uint32_t i = t | ((uint32_t)r << 11);   // expand3<11,12,13>(t)=t
                    v[r] = C2{xrb[i], xib[i]};
                }
            } else {
                const uint32_t sb = slotf(expand3<11,12,13>(t));
                #pragma unroll
                for (int r = 0; r < 8; ++r)
                    v[r] = s[sb ^ slotf(rmask3<11,12,13>(r))];
            }
            rot8<2>(v, GM(li,0)); rot8<1>(v, GM(li,1)); rot8<0>(v, GM(li,2));
            cnot8<2,1>(v); cnot8<1,0>(v);
            const uint32_t sb = slotf(expand3<11,12,13>(t));
            #pragma unroll
            for (int r = 0; r < 8; ++r)
                s[sb ^ slotf(rmask3<11,12,13>(r))] = v[r];
        }
        __syncthreads();

        // sliding 3-bit windows (share 1 qubit with previous): rot 2 + CNOT 2 each
        PASS(9,10,11, rot8<1>(v, GM(li,3));  rot8<0>(v, GM(li,4));  cnot8<2,1>(v); cnot8<1,0>(v);)
        PASS(7,8,9,   rot8<1>(v, GM(li,5));  rot8<0>(v, GM(li,6));  cnot8<2,1>(v); cnot8<1,0>(v);)
        PASS(5,6,7,   rot8<1>(v, GM(li,7));  rot8<0>(v, GM(li,8));  cnot8<2,1>(v); cnot8<1,0>(v);)
        PASS(3,4,5,   rot8<1>(v, GM(li,9));  rot8<0>(v, GM(li,10)); cnot8<2,1>(v); cnot8<1,0>(v);)
        PASS(1,2,3,   rot8<1>(v, GM(li,11)); rot8<0>(v, GM(li,12)); cnot8<2,1>(v); cnot8<1,0>(v);)
        // W7 bits{0,1,13}: L0=bit0(q13), L1=bit1(q12), L2=bit13(q0)
        PASS(0,1,13,  rot8<0>(v, GM(li,13)); cnot8<1,0>(v); cnot8<0,2>(v);)
    }

    // ---- last layer (li=4): rotations only ----
    PASS(11,12,13, rot8<2>(v, GM(4,0)); rot8<1>(v, GM(4,1));  rot8<0>(v, GM(4,2));)
    PASS(8,9,10,   rot8<2>(v, GM(4,3)); rot8<1>(v, GM(4,4));  rot8<0>(v, GM(4,5));)
    PASS(5,6,7,    rot8<2>(v, GM(4,6)); rot8<1>(v, GM(4,7));  rot8<0>(v, GM(4,8));)
    PASS(2,3,4,    rot8<2>(v, GM(4,9)); rot8<1>(v, GM(4,10)); rot8<0>(v, GM(4,11));)

    // final window bits{0,1,2}: rot q12(L1), q13(L0); fuse <Z_0>, no scatter.
    // bit13 of idx = t[10] = slab bit -> per-slab sign.
    float local = 0.f;
    #pragma unroll 1
    for (uint32_t sl = 0; sl < 2; ++sl) {
        const uint32_t t  = tid + sl * BLK;
        const uint32_t sb = slotf(expand3<0,1,2>(t));
        C2 v[8];
        #pragma unroll
        for (int r = 0; r < 8; ++r)
            v[r] = s[sb ^ slotf(rmask3<0,1,2>(r))];
        rot8<1>(v, GM(4,12)); rot8<0>(v, GM(4,13));
        float acc = 0.f;
        #pragma unroll
        for (int r = 0; r < 8; ++r) acc += v[r].x * v[r].x + v[r].y * v[r].y;
        local += sl ? -acc : acc;
    }

    #pragma unroll
    for (int off = 32; off > 0; off >>= 1) local += __shfl_down(local, off);
    const int lane = tid & 63, wid = tid >> 6;
    if (lane == 0) red[wid] = local;
    __syncthreads();
    if (tid == 0) {
        float t = 0.f;
        #pragma unroll
        for (int k = 0; k < BLK / 64; ++k) t += red[k];
        out[b] = t;
    }
}

extern "C" void kernel_launch(void* const* d_in, const int* in_sizes, int n_in,
                              void* d_out, int out_size, void* d_ws, size_t ws_size,
                              hipStream_t stream) {
    const float* xr = (const float*)d_in[0];
    const float* xi = (const float*)d_in[1];
    const float* w  = (const float*)d_in[2];
    float* out = (float*)d_out;
    const int B = out_size;  // 512
    qsim_kernel<<<B, BLK, 0, stream>>>(xr, xi, w, out);
}

// Round 6
// 129.959 us; speedup vs baseline: 2.9285x; 1.5044x over previous
//
#include <hip/hip_runtime.h>
#include <hip/hip_bf16.h>

#define NQ   14
#define DIM  16384      // 2^14
#define BLK  1024
#define WMUL 0.6324555320336759f  // sqrt(2/5)

typedef float v2f __attribute__((ext_vector_type(2)));

struct C2 { float x, y; };  // build-time only
__device__ inline C2 cmulc(C2 a, C2 b){ return C2{a.x*b.x - a.y*b.y, a.x*b.y + a.y*b.x}; }
__device__ inline C2 caddc(C2 a, C2 b){ return C2{a.x+b.x, a.y+b.y}; }
__device__ inline void mm2(const C2* a, const C2* b, C2* o) {
    o[0] = caddc(cmulc(a[0],b[0]), cmulc(a[1],b[2]));
    o[1] = caddc(cmulc(a[0],b[1]), cmulc(a[1],b[3]));
    o[2] = caddc(cmulc(a[2],b[0]), cmulc(a[3],b[2]));
    o[3] = caddc(cmulc(a[2],b[1]), cmulc(a[3],b[3]));
}
__device__ inline void build_gate(int ty, float t, C2* g) {
    float sn, cs;
    __sincosf(0.5f * t, &sn, &cs);
    if (ty == 0) {        // rx
        g[0] = C2{cs, 0.f}; g[1] = C2{0.f, -sn};
        g[2] = C2{0.f, -sn}; g[3] = C2{cs, 0.f};
    } else if (ty == 1) { // ry
        g[0] = C2{cs, 0.f}; g[1] = C2{-sn, 0.f};
        g[2] = C2{sn, 0.f}; g[3] = C2{cs, 0.f};
    } else {              // rz
        g[0] = C2{cs, -sn}; g[1] = C2{0.f, 0.f};
        g[2] = C2{0.f, 0.f}; g[3] = C2{cs, sn};
    }
}
__device__ const int TYPES[5][3] = {
    {0,1,2},  // XYZ
    {1,2,1},  // YZY
    {2,1,0},  // ZYX
    {0,2,0},  // XZX
    {1,2,1},  // YZY
};

// bank-conflict swizzle; GF(2)-LINEAR: slotf(a|b) = slotf(a)^slotf(b) for disjoint a,b
__device__ inline constexpr uint32_t slotf(uint32_t i){
    return i ^ (((i>>4) ^ (i>>8) ^ (i>>12)) & 15u);
}
template<int B> __device__ inline uint32_t ins0(uint32_t t){
    return ((t & ~((1u<<B)-1u)) << 1) | (t & ((1u<<B)-1u));
}
template<int B0,int B1,int B2> __device__ inline uint32_t expand3(uint32_t t){
    return ins0<B2>(ins0<B1>(ins0<B0>(t)));
}
template<int B0,int B1,int B2> __device__ inline constexpr uint32_t rmask3(int r){
    return ((r&1)?(1u<<B0):0u) | ((r&2)?(1u<<B1):0u) | ((r&4)?(1u<<B2):0u);
}

// packed rotation on local bit J. g = 8 v2f: {mxx, msw} per coeff (00,01,10,11),
// mxx = (m.x,m.x), msw = (-m.y,m.y): cmul(m,a) = mxx*a + msw*a.yx (2 pk_fma)
template<int J>
__device__ inline void rot8(v2f* v, const v2f* __restrict__ g){
    const v2f a00=g[0], b00=g[1], a01=g[2], b01=g[3];
    const v2f a10=g[4], b10=g[5], a11=g[6], b11=g[7];
    #pragma unroll
    for (int r = 0; r < 8; ++r){
        if (!(r & (1 << J))) {
            v2f x0 = v[r], x1 = v[r | (1 << J)];
            v2f s0 = x0.yx, s1 = x1.yx;
            v2f y0 = a00*x0 + b00*s0 + a01*x1 + b01*s1;
            v2f y1 = a10*x0 + b10*s0 + a11*x1 + b11*s1;
            v[r] = y0; v[r | (1<<J)] = y1;
        }
    }
}
// CNOT: control local bit C, target local bit T (register renaming, ~free)
template<int C, int T>
__device__ inline void cnot8(v2f* v){
    #pragma unroll
    for (int r = 0; r < 8; ++r){
        if ((r & (1 << C)) && !(r & (1 << T))) {
            v2f tt = v[r]; v[r] = v[r | (1 << T)]; v[r | (1 << T)] = tt;
        }
    }
}

__global__ __launch_bounds__(BLK) void qsim_kernel(
        const float* __restrict__ xr, const float* __restrict__ xi,
        const float* __restrict__ w, float* __restrict__ out) {
    __shared__ v2f s[DIM];            // 128 KiB statevector (swizzled layout)
    __shared__ v2f gmp[5 * NQ * 8];   // 70 gates, packed-friendly form (4.4 KiB)
    __shared__ float red[BLK / 64];

    const int b   = blockIdx.x;
    const uint32_t tid = threadIdx.x;

    // ---- build fused gate matrices (threads 0..69), store packed form ----
    if (tid < 5 * NQ) {
        const int li = tid / NQ, q = tid % NQ;
        C2 M[4], G[4], T[4];
        #pragma unroll
        for (int j = 0; j < 3; ++j) {
            float t = w[3 * NQ * li + 3 * q + j] * WMUL;
            build_gate(TYPES[li][j], t, G);
            if (j == 0) { M[0]=G[0]; M[1]=G[1]; M[2]=G[2]; M[3]=G[3]; }
            else { mm2(G, M, T); M[0]=T[0]; M[1]=T[1]; M[2]=T[2]; M[3]=T[3]; }
        }
        #pragma unroll
        for (int k = 0; k < 4; ++k) {
            gmp[tid * 8 + k * 2 + 0] = v2f{ M[k].x, M[k].x};
            gmp[tid * 8 + k * 2 + 1] = v2f{-M[k].y, M[k].y};
        }
    }
    __syncthreads();

    const float* xrb = xr + (size_t)b * DIM;
    const float* xib = xi + (size_t)b * DIM;

    // qubit q <-> bit (13-q).
    #define GMP(li, q) (&gmp[((li) * NQ + (q)) * 8])

    // One pass: 2 sequential slabs (live state = v2f v[8] = 16 VGPRs).
    #define PASS(B0, B1, B2, ...)                                                  \
        _Pragma("unroll 1")                                                        \
        for (uint32_t sl = 0; sl < 2; ++sl) {                                      \
            const uint32_t t  = tid + sl * BLK;                                    \
            const uint32_t sb = slotf(expand3<B0,B1,B2>(t));                       \
            v2f v[8];                                                              \
            _Pragma("unroll")                                                      \
            for (int r = 0; r < 8; ++r)                                            \
                v[r] = s[sb ^ slotf(rmask3<B0,B1,B2>(r))];                         \
            __VA_ARGS__                                                            \
            _Pragma("unroll")                                                      \
            for (int r = 0; r < 8; ++r)                                            \
                s[sb ^ slotf(rmask3<B0,B1,B2>(r))] = v[r];                         \
        }                                                                          \
        __syncthreads();

    // ---- layers 0..2: 7 windows each (rot(li) + ring CNOTs chained) ----
    #pragma unroll 1
    for (int li = 0; li < 3; ++li) {
        // W1 bits{11,12,13}: L2=q0, L1=q1, L0=q2
        #pragma unroll 1
        for (uint32_t sl = 0; sl < 2; ++sl) {
            const uint32_t t = tid + sl * BLK;
            v2f v[8];
            if (li == 0) {
                #pragma unroll
                for (int r = 0; r < 8; ++r) {
                    uint32_t i = t | ((uint32_t)r << 11);   // expand3<11,12,13>(t)=t
                    v[r] = v2f{xrb[i], xib[i]};
                }
            } else {
                const uint32_t sb = slotf(expand3<11,12,13>(t));
                #pragma unroll
                for (int r = 0; r < 8; ++r)
                    v[r] = s[sb ^ slotf(rmask3<11,12,13>(r))];
            }
            rot8<2>(v, GMP(li,0)); rot8<1>(v, GMP(li,1)); rot8<0>(v, GMP(li,2));
            cnot8<2,1>(v); cnot8<1,0>(v);
            const uint32_t sb = slotf(expand3<11,12,13>(t));
            #pragma unroll
            for (int r = 0; r < 8; ++r)
                s[sb ^ slotf(rmask3<11,12,13>(r))] = v[r];
        }
        __syncthreads();

        PASS(9,10,11, rot8<1>(v, GMP(li,3));  rot8<0>(v, GMP(li,4));  cnot8<2,1>(v); cnot8<1,0>(v);)
        PASS(7,8,9,   rot8<1>(v, GMP(li,5));  rot8<0>(v, GMP(li,6));  cnot8<2,1>(v); cnot8<1,0>(v);)
        PASS(5,6,7,   rot8<1>(v, GMP(li,7));  rot8<0>(v, GMP(li,8));  cnot8<2,1>(v); cnot8<1,0>(v);)
        PASS(3,4,5,   rot8<1>(v, GMP(li,9));  rot8<0>(v, GMP(li,10)); cnot8<2,1>(v); cnot8<1,0>(v);)
        PASS(1,2,3,   rot8<1>(v, GMP(li,11)); rot8<0>(v, GMP(li,12)); cnot8<2,1>(v); cnot8<1,0>(v);)
        // W7 bits{0,1,13}: L0=q13, L1=q12, L2=q0
        PASS(0,1,13,  rot8<0>(v, GMP(li,13)); cnot8<1,0>(v); cnot8<0,2>(v);)
    }

    // ---- layer 3 ring windows, with layer-4 rotations folded in where both
    //      ring CNOTs touching the qubit are done (later ring gates commute) ----
    PASS(11,12,13, rot8<2>(v, GMP(3,0));  rot8<1>(v, GMP(3,1));  rot8<0>(v, GMP(3,2));
                   cnot8<2,1>(v); cnot8<1,0>(v);
                   rot8<1>(v, GMP(4,1));)
    PASS(9,10,11,  rot8<1>(v, GMP(3,3));  rot8<0>(v, GMP(3,4));
                   cnot8<2,1>(v); cnot8<1,0>(v);
                   rot8<2>(v, GMP(4,2));  rot8<1>(v, GMP(4,3));)
    PASS(7,8,9,    rot8<1>(v, GMP(3,5));  rot8<0>(v, GMP(3,6));
                   cnot8<2,1>(v); cnot8<1,0>(v);
                   rot8<2>(v, GMP(4,4));  rot8<1>(v, GMP(4,5));)
    PASS(5,6,7,    rot8<1>(v, GMP(3,7));  rot8<0>(v, GMP(3,8));
                   cnot8<2,1>(v); cnot8<1,0>(v);
                   rot8<2>(v, GMP(4,6));  rot8<1>(v, GMP(4,7));)
    PASS(3,4,5,    rot8<1>(v, GMP(3,9));  rot8<0>(v, GMP(3,10));
                   cnot8<2,1>(v); cnot8<1,0>(v);
                   rot8<2>(v, GMP(4,8));  rot8<1>(v, GMP(4,9));)
    PASS(1,2,3,    rot8<1>(v, GMP(3,11)); rot8<0>(v, GMP(3,12));
                   cnot8<2,1>(v); cnot8<1,0>(v);
                   rot8<2>(v, GMP(4,10)); rot8<1>(v, GMP(4,11));)

    // final window bits{0,1,13}: L0=q13, L1=q12, L2=q0.
    // rot3(q13); CNOT(12,13); CNOT(13,0); rot4(q12,q13,q0); fused <Z_0>, no scatter.
    // sign: idx bit13 (q0) = local bit 2 = (r&4).
    float local = 0.f;
    #pragma unroll 1
    for (uint32_t sl = 0; sl < 2; ++sl) {
        const uint32_t t  = tid + sl * BLK;
        const uint32_t sb = slotf(expand3<0,1,13>(t));
        v2f v[8];
        #pragma unroll
        for (int r = 0; r < 8; ++r)
            v[r] = s[sb ^ slotf(rmask3<0,1,13>(r))];
        rot8<0>(v, GMP(3,13));
        cnot8<1,0>(v); cnot8<0,2>(v);
        rot8<1>(v, GMP(4,12)); rot8<0>(v, GMP(4,13)); rot8<2>(v, GMP(4,0));
        #pragma unroll
        for (int r = 0; r < 8; ++r) {
            v2f p = v[r] * v[r];
            float m = p.x + p.y;
            local += (r & 4) ? -m : m;
        }
    }

    #pragma unroll
    for (int off = 32; off > 0; off >>= 1) local += __shfl_down(local, off);
    const int lane = tid & 63, wid = tid >> 6;
    if (lane == 0) red[wid] = local;
    __syncthreads();
    if (tid == 0) {
        float t = 0.f;
        #pragma unroll
        for (int k = 0; k < BLK / 64; ++k) t += red[k];
        out[b] = t;
    }
}

extern "C" void kernel_launch(void* const* d_in, const int* in_sizes, int n_in,
                              void* d_out, int out_size, void* d_ws, size_t ws_size,
                              hipStream_t stream) {
    const float* xr = (const float*)d_in[0];
    const float* xi = (const float*)d_in[1];
    const float* w  = (const float*)d_in[2];
    float* out = (float*)d_out;
    const int B = out_size;  // 512
    qsim_kernel<<<B, BLK, 0, stream>>>(xr, xi, w, out);
}